// Round 9
// baseline (604.260 us; speedup 1.0000x reference)
//
#include <hip/hip_runtime.h>

constexpr int N    = 50000;
constexpr int E    = 800000;
constexpr int NG   = 64;
constexpr int ODIM = 10;
constexpr int OUTC = 128;
constexpr int GP_BLOCKS = 256;
constexpr int SCAN_B = (N + 255) / 256;   // 196
constexpr int CS1B   = 784;               // colsum stage-1 blocks
constexpr float SCALE    = 32768.0f;      // 2^15 for U = D^-1/2 Z (fp8 e4m3)
constexpr float INVSCALE = 1.0f / SCALE;

// chunk x range LDS-histogram CSR build (r1-proven: no global atomics)
// r9: CNT_R 8 -> 4 (48.8 KB LDS) halves the ei re-read volume in k_count.
constexpr int CNT_C = 16;                 // edge chunks
constexpr int CHUNK = E / CNT_C;          // 50000
constexpr int CNT_R = 4;                  // node ranges
constexpr int RANGE = N / CNT_R;          // 12500 (48.8 KB LDS histogram)
constexpr int HV4   = CHUNK / 8;          // 6250 int4 pairs per chunk array

constexpr int PROP_BLOCKS = (N * 8 + 255) / 256;          // 1563

typedef float floatx2 __attribute__((ext_vector_type(2)));

// ---------- fp8 e4m3 helpers (r9-proven) ----------
__device__ __forceinline__ void unp4(unsigned int u, float* f) {
    floatx2 lo = __builtin_amdgcn_cvt_pk_f32_fp8(u, false);
    floatx2 hi = __builtin_amdgcn_cvt_pk_f32_fp8(u, true);
    f[0] = lo.x; f[1] = lo.y; f[2] = hi.x; f[3] = hi.y;
}
__device__ __forceinline__ unsigned int pk4(float a, float b, float c, float d) {
    int r = __builtin_amdgcn_cvt_pk_fp8_f32(a, b, 0, false);
    r = __builtin_amdgcn_cvt_pk_fp8_f32(c, d, r, true);
    return (unsigned int)r;
}

// ---------- CSR count via LDS histograms: NO global atomics ----------
__device__ __forceinline__ void cnt4_src(int4 v, int lo, int* h,
                                         int* __restrict__ pos_e, int e) {
    if ((unsigned)(v.x - lo) < (unsigned)RANGE) pos_e[e]     = atomicAdd(&h[v.x - lo], 1);
    if ((unsigned)(v.y - lo) < (unsigned)RANGE) pos_e[e + 1] = atomicAdd(&h[v.y - lo], 1);
    if ((unsigned)(v.z - lo) < (unsigned)RANGE) pos_e[e + 2] = atomicAdd(&h[v.z - lo], 1);
    if ((unsigned)(v.w - lo) < (unsigned)RANGE) pos_e[e + 3] = atomicAdd(&h[v.w - lo], 1);
}
__device__ __forceinline__ void cnt4_dst(int4 v, int lo, int* h) {
    if ((unsigned)(v.x - lo) < (unsigned)RANGE) atomicAdd(&h[v.x - lo], 1);
    if ((unsigned)(v.y - lo) < (unsigned)RANGE) atomicAdd(&h[v.y - lo], 1);
    if ((unsigned)(v.z - lo) < (unsigned)RANGE) atomicAdd(&h[v.z - lo], 1);
    if ((unsigned)(v.w - lo) < (unsigned)RANGE) atomicAdd(&h[v.w - lo], 1);
}

// grid = CNT_C * CNT_R * 2 = 128 blocks. block (c, r, kind).
__global__ __launch_bounds__(512) void k_count(const int* __restrict__ ei,
        int* __restrict__ cnt16, int* __restrict__ deg16, int* __restrict__ pos_e) {
    __shared__ int h[RANGE];
    int bid  = blockIdx.x;
    int c    = bid & 15;
    int r    = (bid >> 4) & 3;
    int kind = bid >> 6;
    int tid  = threadIdx.x;
    for (int i = tid; i < RANGE; i += 512) h[i] = 0;
    __syncthreads();
    int lo = r * RANGE;
    const int4* src = (const int4*)(ei + (size_t)kind * E + (size_t)c * CHUNK);
    int ebase = c * CHUNK;
    if (kind == 0) {
        for (int i = tid; i < HV4; i += 512) {
            int4 a = src[i];
            int4 b = src[i + HV4];
            cnt4_src(a, lo, h, pos_e, ebase + i * 4);
            cnt4_src(b, lo, h, pos_e, ebase + (i + HV4) * 4);
        }
    } else {
        for (int i = tid; i < HV4; i += 512) {
            int4 a = src[i];
            int4 b = src[i + HV4];
            cnt4_dst(a, lo, h);
            cnt4_dst(b, lo, h);
        }
    }
    __syncthreads();
    int* dst = (kind == 0 ? cnt16 : deg16) + (size_t)c * N + lo;
    for (int i = tid; i < RANGE; i += 512) dst[i] = h[i];
}

// fused: 16-copy reduce (deg, cnt, per-copy bases) + scales + block scan
__global__ void k_scan1(const int* __restrict__ cnt16, int* __restrict__ base16,
                        int* __restrict__ off, int* bsum,
                        const int* __restrict__ deg16, float* wsq, float* sdeg) {
    __shared__ int buf[256];
    int tid = threadIdx.x;
    int i = blockIdx.x * 256 + tid;
    int total = 0;
    if (i < N) {
        int run = 0;
        #pragma unroll
        for (int q = 0; q < CNT_C; ++q) {
            base16[q * N + i] = run;
            run += cnt16[q * N + i];
        }
        total = run;
        int deg = 1;                               // self loop
        #pragma unroll
        for (int q = 0; q < CNT_C; ++q) deg += deg16[q * N + i];
        float d = (float)deg;
        wsq[i]  = 1.0f / d;
        sdeg[i] = sqrtf(d);
    }
    buf[tid] = total;
    __syncthreads();
    for (int s = 1; s < 256; s <<= 1) {
        int add = (tid >= s) ? buf[tid - s] : 0;
        __syncthreads();
        buf[tid] += add;
        __syncthreads();
    }
    if (i < N) off[i] = buf[tid] - total;
    if (tid == 255) bsum[blockIdx.x] = buf[255];
}

// r9 fused scan2+scan3 + cntg(binary search over sorted batch) + svec/ctr init.
// Every block redundantly scans the 196 block-sums (L2-hit cheap) and applies
// its own prefix to off[]; block 0 also does the one-off small inits.
__global__ void k_scan23(int* __restrict__ off, const int* __restrict__ bsum,
                         const int* __restrict__ batch, int* __restrict__ cntg,
                         float* __restrict__ svec, int* __restrict__ csctr) {
    __shared__ int buf[256];
    __shared__ int sL[65];
    int tid = threadIdx.x;
    int v = (tid < SCAN_B) ? bsum[tid] : 0;
    buf[tid] = v;
    __syncthreads();
    for (int s = 1; s < 256; s <<= 1) {
        int add = (tid >= s) ? buf[tid - s] : 0;
        __syncthreads();
        buf[tid] += add;
        __syncthreads();
    }
    int bid = blockIdx.x;
    int pre = buf[bid] - bsum[bid];               // exclusive prefix for this block
    int i = bid * 256 + tid;
    if (i < N) off[i] += pre;
    if (bid == 0) {
        if (tid == 0) off[N] = E;
        // cntg[g] via binary search: batch is sorted ascending in [0, NG)
        if (tid < NG) {
            int lo = 0, hi = N;
            while (lo < hi) {
                int mid = (lo + hi) >> 1;
                if (batch[mid] < tid) lo = mid + 1; else hi = mid;
            }
            sL[tid] = lo;
            if (tid == 0) sL[NG] = N;
        }
        if (tid >= 64 && tid < 192) svec[tid - 64] = 0.f;
        if (tid == 192) { csctr[0] = 0; csctr[1] = 0; }
        __syncthreads();
        if (tid < NG) cntg[tid] = sL[tid + 1] - sL[tid];
    }
}

// fused: CSR fill (e<E, slot via per-copy base) + U0 row init (e<N)
__global__ void k_fill(const int* __restrict__ ei, const int* __restrict__ off,
                       const int* __restrict__ base16, const int* __restrict__ pos_e,
                       int* __restrict__ mdst,
                       const int* __restrict__ batch, const int* __restrict__ cntg,
                       const float* __restrict__ sdeg, uint4* Z0) {
    int e = blockIdx.x * 256 + threadIdx.x;
    if (e < E) {
        int s = ei[e];
        int q = e / CHUNK;                         // matches k_count's chunking
        mdst[off[s] + base16[q * N + s] + pos_e[e]] = ei[E + e];
    }
    if (e < N) {
        int i = e;
        int g = batch[i];
        int c = cntg[g]; if (c < 1) c = 1;
        float v = (SCALE / (float)c) / sdeg[i];    // dinv = 1/sqrt(deg)
        unsigned int byte = (unsigned int)(__builtin_amdgcn_cvt_pk_fp8_f32(v, v, 0, false) & 0xFF);
        uint4 rows[4];
        #pragma unroll
        for (int q = 0; q < 4; ++q) rows[q] = make_uint4(0u, 0u, 0u, 0u);
        unsigned int* wp = (unsigned int*)rows;
        wp[g >> 2] = byte << (8 * (g & 3));
        #pragma unroll
        for (int q = 0; q < 4; ++q) Z0[(size_t)i * 4 + q] = rows[q];
    }
}

// ---------- hot kernel (r8-frozen): 8 c-lanes/node + int4 idx + 12-deep bursts ----------
__device__ __forceinline__ void add8(floatx2* a, uint2 g) {
    a[0] += __builtin_amdgcn_cvt_pk_f32_fp8(g.x, false);
    a[1] += __builtin_amdgcn_cvt_pk_f32_fp8(g.x, true);
    a[2] += __builtin_amdgcn_cvt_pk_f32_fp8(g.y, false);
    a[3] += __builtin_amdgcn_cvt_pk_f32_fp8(g.y, true);
}

__global__ __launch_bounds__(256, 8) void k_prop(
        const uint2* __restrict__ zin, unsigned long long* __restrict__ zout,
        const int* __restrict__ off, const int* __restrict__ mdst,
        const float* __restrict__ wsq) {
    int t = blockIdx.x * 256 + threadIdx.x;      // N*8 threads
    int node = t >> 3;
    int c    = t & 7;
    if (node >= N) return;                       // no barrier: safe

    floatx2 acc[4];
    #pragma unroll
    for (int k = 0; k < 4; ++k) acc[k] = (floatx2){0.f, 0.f};

    int e  = off[node];
    int e1 = off[node + 1];
    add8(acc, zin[(size_t)node * 8 + c]);        // self term (unweighted in U-form)

    for (; e + 11 < e1; e += 12) {               // 12 gathers in flight
        int4 ia = *(const int4*)(mdst + e);      // 3 vector idx loads
        int4 ib = *(const int4*)(mdst + e + 4);
        int4 ic = *(const int4*)(mdst + e + 8);
        uint2 g0 = zin[(size_t)ia.x * 8 + c];
        uint2 g1 = zin[(size_t)ia.y * 8 + c];
        uint2 g2 = zin[(size_t)ia.z * 8 + c];
        uint2 g3 = zin[(size_t)ia.w * 8 + c];
        uint2 g4 = zin[(size_t)ib.x * 8 + c];
        uint2 g5 = zin[(size_t)ib.y * 8 + c];
        uint2 g6 = zin[(size_t)ib.z * 8 + c];
        uint2 g7 = zin[(size_t)ib.w * 8 + c];
        uint2 g8 = zin[(size_t)ic.x * 8 + c];
        uint2 g9 = zin[(size_t)ic.y * 8 + c];
        uint2 ga = zin[(size_t)ic.z * 8 + c];
        uint2 gb = zin[(size_t)ic.w * 8 + c];
        add8(acc, g0); add8(acc, g1); add8(acc, g2); add8(acc, g3);
        add8(acc, g4); add8(acc, g5); add8(acc, g6); add8(acc, g7);
        add8(acc, g8); add8(acc, g9); add8(acc, ga); add8(acc, gb);
    }
    for (; e + 3 < e1; e += 4) {
        int4 ia = *(const int4*)(mdst + e);
        uint2 g0 = zin[(size_t)ia.x * 8 + c];
        uint2 g1 = zin[(size_t)ia.y * 8 + c];
        uint2 g2 = zin[(size_t)ia.z * 8 + c];
        uint2 g3 = zin[(size_t)ia.w * 8 + c];
        add8(acc, g0); add8(acc, g1); add8(acc, g2); add8(acc, g3);
    }
    for (; e < e1; ++e) {
        add8(acc, zin[(size_t)mdst[e] * 8 + c]);
    }

    float ws = wsq[node];
    unsigned int w0 = pk4(ws * acc[0].x, ws * acc[0].y, ws * acc[1].x, ws * acc[1].y);
    unsigned int w1 = pk4(ws * acc[2].x, ws * acc[2].y, ws * acc[3].x, ws * acc[3].y);
    unsigned long long o = (unsigned long long)w0 | ((unsigned long long)w1 << 32);
    __builtin_nontemporal_store(o, &zout[(size_t)node * 8 + c]);
}

// ---------- colsum: fused two-stage via last-block pattern (r9) ----------
// stage1 blocks write part2, release-fence + count; last block acquire-fences
// and reduces 64 columns x CS1B partials into sdst. -2 dispatches.
__global__ void k_colsum(const unsigned int* __restrict__ Z,
                         const float* __restrict__ sdeg, float* __restrict__ part2,
                         int* __restrict__ ctr, float* __restrict__ sdst) {
    __shared__ float red[256];
    __shared__ int lastflag;
    int g = threadIdx.x & 63, sub = threadIdx.x >> 6;
    int w = g >> 2;
    int word = (g >> 1) & 1;
    int odd  = g & 1;
    float acc = 0.f;
    for (int i = blockIdx.x * 4 + sub; i < N; i += gridDim.x * 4) {
        unsigned int u = Z[(size_t)i * 16 + w];
        floatx2 p = word ? __builtin_amdgcn_cvt_pk_f32_fp8(u, true)
                         : __builtin_amdgcn_cvt_pk_f32_fp8(u, false);
        acc += (odd ? p.y : p.x) * sdeg[i];
    }
    red[threadIdx.x] = acc;
    __syncthreads();
    if (sub == 0)
        part2[g * CS1B + blockIdx.x] = red[g] + red[64 + g] + red[128 + g] + red[192 + g];
    __threadfence();                              // release part2 writes (agent scope)
    if (threadIdx.x == 0)
        lastflag = (atomicAdd(ctr, 1) == (int)gridDim.x - 1);
    __syncthreads();
    if (!lastflag) return;
    __threadfence();                              // acquire: see all part2 writes
    float a2 = 0.f;
    for (int b = sub; b < CS1B; b += 4) a2 += part2[g * CS1B + b];
    red[threadIdx.x] = a2;
    __syncthreads();
    if (sub == 0)
        sdst[g] = (red[g] + red[64 + g] + red[128 + g] + red[192 + g]) * INVSCALE;
}

// partial G = (sdeg .* U15)^T X
__global__ __launch_bounds__(256) void k_gpart(
        const uint4* __restrict__ Z, const float4* __restrict__ X,
        const float* __restrict__ sdeg, float* part) {
    __shared__ unsigned int zr[32][16];
    __shared__ float xr[32][128];
    __shared__ float sd[32];
    int tid = threadIdx.x;
    int f4 = tid & 31;
    int gs = tid >> 5;
    float4 acc[8];
    #pragma unroll
    for (int k = 0; k < 8; ++k) acc[k] = make_float4(0.f, 0.f, 0.f, 0.f);

    int per = (N + gridDim.x - 1) / gridDim.x;
    int n0 = blockIdx.x * per;
    int n1 = n0 + per; if (n1 > N) n1 = N;

    for (int nb = n0; nb < n1; nb += 32) {
        __syncthreads();
        if (tid < 128) {
            int nn = tid >> 2, q = tid & 3;
            int node = nb + nn;
            uint4 zv = make_uint4(0u, 0u, 0u, 0u);
            if (node < n1) zv = Z[(size_t)node * 4 + q];
            ((uint4*)&zr[nn][0])[q] = zv;
        }
        if (tid >= 192 && tid < 224) {
            int node = nb + (tid - 192);
            sd[tid - 192] = (node < n1) ? sdeg[node] : 0.f;
        }
        #pragma unroll
        for (int r = 0; r < 4; ++r) {
            int l = r * 256 + tid;
            int nn = l >> 5, c4 = l & 31;
            int node = nb + nn;
            float4 xv = make_float4(0.f, 0.f, 0.f, 0.f);
            if (node < n1) xv = X[(size_t)node * 32 + c4];
            ((float4*)&xr[nn][0])[c4] = xv;
        }
        __syncthreads();
        for (int nn = 0; nn < 32; ++nn) {
            float sc = sd[nn];
            float4 xv = ((const float4*)&xr[nn][0])[f4];
            xv.x *= sc; xv.y *= sc; xv.z *= sc; xv.w *= sc;
            unsigned int za = zr[nn][gs * 2], zb = zr[nn][gs * 2 + 1];
            float zf[8];
            unp4(za, zf); unp4(zb, zf + 4);
            #pragma unroll
            for (int k = 0; k < 8; ++k) {
                acc[k].x += zf[k] * xv.x; acc[k].y += zf[k] * xv.y;
                acc[k].z += zf[k] * xv.z; acc[k].w += zf[k] * xv.w;
            }
        }
    }
    float4* dst = (float4*)(part + (size_t)blockIdx.x * 8192);
    #pragma unroll
    for (int k = 0; k < 8; ++k) dst[(gs * 8 + k) * 32 + f4] = acc[k];
}

__global__ void k_greduce(const float4* __restrict__ part, float4* G) {
    __shared__ float4 red[256];
    int tid = threadIdx.x;
    int o4 = blockIdx.x * 16 + (tid & 15);
    int slice = tid >> 4;
    float4 a = make_float4(0.f, 0.f, 0.f, 0.f);
    #pragma unroll 4
    for (int k = 0; k < GP_BLOCKS / 16; ++k) {
        float4 v = part[(size_t)(slice * (GP_BLOCKS / 16) + k) * 2048 + o4];
        a.x += v.x; a.y += v.y; a.z += v.z; a.w += v.w;
    }
    red[tid] = a;
    __syncthreads();
    for (int s = 128; s >= 16; s >>= 1) {
        if (tid < s) {
            float4 b = red[tid + s];
            red[tid].x += b.x; red[tid].y += b.y; red[tid].z += b.z; red[tid].w += b.w;
        }
        __syncthreads();
    }
    if (tid < 16) {
        float4 r = red[tid];
        G[o4] = make_float4(r.x * INVSCALE, r.y * INVSCALE, r.z * INVSCALE, r.w * INVSCALE);
    }
}

// pass1: [W1;b1] (129x160) @ W2 (160x160) -> T1c
__global__ void k_pass1(const float* __restrict__ W1, const float* __restrict__ b1,
                        const float* __restrict__ W2, float* T1c) {
    int t = blockIdx.x * 256 + threadIdx.x;
    if (t >= 129 * 160) return;
    int m = t / 160, c = t - m * 160;
    const float* arow = (m < 128) ? (W1 + m * 160) : b1;
    float a = 0.f;
    for (int k = 0; k < 160; ++k) a += arow[k] * W2[k * 160 + c];
    T1c[t] = a;
}

// pass2: [T1c; b2] (130x160) @ W3 (160x128) -> TWc
__global__ void k_pass2(const float* __restrict__ T1c, const float* __restrict__ b2,
                        const float* __restrict__ W3, float* TWc) {
    int t = blockIdx.x * 256 + threadIdx.x;
    if (t >= 130 * 128) return;
    int m = t >> 7, c = t & 127;
    const float* arow = (m < 129) ? (T1c + m * 160) : b2;
    float a = 0.f;
    for (int k = 0; k < 160; ++k) a += arow[k] * W3[k * 128 + c];
    TWc[t] = a;
}

__global__ void k_pooled(const float* __restrict__ G, const float* __restrict__ TWc,
                         const float* __restrict__ b3, const float* __restrict__ svec,
                         float* pooled) {
    int t = blockIdx.x * 256 + threadIdx.x;
    if (t >= NG * OUTC) return;
    int g = t >> 7, f = t & 127;
    float a = b3[f] + svec[64 + g] * TWc[128 * 128 + f] + svec[g] * TWc[129 * 128 + f];
    for (int k = 0; k < 128; ++k) a += G[g * 128 + k] * TWc[k * 128 + f];
    pooled[t] = a;
}

__global__ void k_head(const float* __restrict__ pooled, const float* __restrict__ fcw,
                       const float* __restrict__ fcb, float* out) {
    __shared__ float lg[ODIM];
    int g = blockIdx.x, tid = threadIdx.x;
    if (tid < ODIM) {
        float a = fcb[tid];
        for (int k = 0; k < 128; ++k) a += pooled[g * 128 + k] * fcw[k * ODIM + tid];
        lg[tid] = a;
    }
    __syncthreads();
    if (tid == 0) {
        float mx = lg[0];
        for (int j = 1; j < ODIM; ++j) mx = fmaxf(mx, lg[j]);
        float sum = 0.f;
        for (int j = 0; j < ODIM; ++j) sum += expf(lg[j] - mx);
        float lse = mx + logf(sum);
        for (int j = 0; j < ODIM; ++j) out[g * ODIM + j] = lg[j] - lse;
    }
}

extern "C" void kernel_launch(void* const* d_in, const int* in_sizes, int n_in,
                              void* d_out, int out_size, void* d_ws, size_t ws_size,
                              hipStream_t stream) {
    const float* x    = (const float*)d_in[0];
    const int*   ei   = (const int*)d_in[1];
    const int*   batch= (const int*)d_in[2];
    const float* W1   = (const float*)d_in[3];
    const float* b1   = (const float*)d_in[4];
    const float* W2   = (const float*)d_in[5];
    const float* b2   = (const float*)d_in[6];
    const float* W3   = (const float*)d_in[7];
    const float* b3   = (const float*)d_in[8];
    const float* fcw  = (const float*)d_in[9];
    const float* fcb  = (const float*)d_in[10];
    float* out = (float*)d_out;

    char* p = (char*)d_ws;
    auto alloc = [&](size_t bytes) -> void* {
        void* r = (void*)p;
        p += (bytes + 255) & ~(size_t)255;
        return r;
    };
    int*   cnt16   = (int*)  alloc((size_t)CNT_C * N * 4);  // fully written by k_count
    int*   deg16   = (int*)  alloc((size_t)CNT_C * N * 4);  // fully written by k_count
    int*   base16  = (int*)  alloc((size_t)CNT_C * N * 4);
    float* wsq     = (float*)alloc((size_t)N * 4);
    float* sdeg    = (float*)alloc((size_t)N * 4);
    int*   off     = (int*)  alloc((size_t)(N + 1) * 4);
    int*   bsum    = (int*)  alloc((size_t)SCAN_B * 4);
    int*   pos_e   = (int*)  alloc((size_t)E * 4);
    int*   mdst    = (int*)  alloc((size_t)E * 4);
    int*   cntg    = (int*)  alloc((size_t)NG * 4);
    float* svec    = (float*)alloc(128 * 4);
    int*   csctr   = (int*)  alloc(2 * 4);
    unsigned char* Z0 = (unsigned char*)alloc((size_t)N * 64);
    unsigned char* Z1 = (unsigned char*)alloc((size_t)N * 64);
    float* part    = (float*)alloc((size_t)GP_BLOCKS * 8192 * 4);
    float* G       = (float*)alloc(8192 * 4);
    float* T1c     = (float*)alloc(129 * 160 * 4);
    float* TWc     = (float*)alloc(130 * 128 * 4);
    float* pooled  = (float*)alloc(64 * 128 * 4);

    int nb_e = (E + 255) / 256;
    k_count<<<CNT_C * CNT_R * 2, 512, 0, stream>>>(ei, cnt16, deg16, pos_e);
    k_scan1<<<SCAN_B, 256, 0, stream>>>(cnt16, base16, off, bsum, deg16, wsq, sdeg);
    k_scan23<<<SCAN_B, 256, 0, stream>>>(off, bsum, batch, cntg, svec, csctr);
    k_fill<<<nb_e, 256, 0, stream>>>(ei, off, base16, pos_e, mdst, batch, cntg, sdeg, (uint4*)Z0);

    unsigned char* zc = Z0;
    unsigned char* zn = Z1;
    for (int hop = 1; hop <= 15; ++hop) {
        k_prop<<<PROP_BLOCKS, 256, 0, stream>>>(
            (const uint2*)zc, (unsigned long long*)zn, off, mdst, wsq);
        unsigned char* t = zc; zc = zn; zn = t;
        if (hop == 5) {
            k_colsum<<<CS1B, 256, 0, stream>>>((const unsigned int*)zc, sdeg, part,
                                               csctr, svec);
        }
        if (hop == 10) {
            k_colsum<<<CS1B, 256, 0, stream>>>((const unsigned int*)zc, sdeg, part,
                                               csctr + 1, svec + 64);
        }
    }

    k_gpart<<<GP_BLOCKS, 256, 0, stream>>>((const uint4*)zc, (const float4*)x, sdeg, part);
    k_greduce<<<128, 256, 0, stream>>>((const float4*)part, (float4*)G);

    k_pass1<<<(129 * 160 + 255) / 256, 256, 0, stream>>>(W1, b1, W2, T1c);
    k_pass2<<<(130 * 128 + 255) / 256, 256, 0, stream>>>(T1c, b2, W3, TWc);
    k_pooled<<<32, 256, 0, stream>>>(G, TWc, b3, svec, pooled);
    k_head<<<NG, 64, 0, stream>>>(pooled, fcw, fcb, out);
}

// Round 10
// 405.542 us; speedup vs baseline: 1.4900x; 1.4900x over previous
//
#include <hip/hip_runtime.h>

constexpr int N    = 50000;
constexpr int E    = 800000;
constexpr int NG   = 64;
constexpr int ODIM = 10;
constexpr int OUTC = 128;
constexpr int GP_BLOCKS = 256;
constexpr int SCAN_B = (N + 255) / 256;   // 196
constexpr int CS1B   = 784;               // colsum stage-1 blocks
constexpr float SCALE    = 32768.0f;      // 2^15 for U = D^-1/2 Z (fp8 e4m3)
constexpr float INVSCALE = 1.0f / SCALE;

// chunk x range LDS-histogram CSR build (r1-proven: no global atomics)
// r9-kept: CNT_R=4 (48.8 KB LDS) halves the ei re-read volume in k_count.
constexpr int CNT_C = 16;                 // edge chunks
constexpr int CHUNK = E / CNT_C;          // 50000
constexpr int CNT_R = 4;                  // node ranges
constexpr int RANGE = N / CNT_R;          // 12500 (48.8 KB LDS histogram)
constexpr int HV4   = CHUNK / 8;          // 6250 int4 pairs per chunk array

constexpr int PROP_BLOCKS = (N * 8 + 255) / 256;          // 1563

typedef float floatx2 __attribute__((ext_vector_type(2)));

// ---------- fp8 e4m3 helpers (r9-proven) ----------
__device__ __forceinline__ void unp4(unsigned int u, float* f) {
    floatx2 lo = __builtin_amdgcn_cvt_pk_f32_fp8(u, false);
    floatx2 hi = __builtin_amdgcn_cvt_pk_f32_fp8(u, true);
    f[0] = lo.x; f[1] = lo.y; f[2] = hi.x; f[3] = hi.y;
}
__device__ __forceinline__ unsigned int pk4(float a, float b, float c, float d) {
    int r = __builtin_amdgcn_cvt_pk_fp8_f32(a, b, 0, false);
    r = __builtin_amdgcn_cvt_pk_fp8_f32(c, d, r, true);
    return (unsigned int)r;
}

// ---------- CSR count via LDS histograms: NO global atomics ----------
__device__ __forceinline__ void cnt4_src(int4 v, int lo, int* h,
                                         int* __restrict__ pos_e, int e) {
    if ((unsigned)(v.x - lo) < (unsigned)RANGE) pos_e[e]     = atomicAdd(&h[v.x - lo], 1);
    if ((unsigned)(v.y - lo) < (unsigned)RANGE) pos_e[e + 1] = atomicAdd(&h[v.y - lo], 1);
    if ((unsigned)(v.z - lo) < (unsigned)RANGE) pos_e[e + 2] = atomicAdd(&h[v.z - lo], 1);
    if ((unsigned)(v.w - lo) < (unsigned)RANGE) pos_e[e + 3] = atomicAdd(&h[v.w - lo], 1);
}
__device__ __forceinline__ void cnt4_dst(int4 v, int lo, int* h) {
    if ((unsigned)(v.x - lo) < (unsigned)RANGE) atomicAdd(&h[v.x - lo], 1);
    if ((unsigned)(v.y - lo) < (unsigned)RANGE) atomicAdd(&h[v.y - lo], 1);
    if ((unsigned)(v.z - lo) < (unsigned)RANGE) atomicAdd(&h[v.z - lo], 1);
    if ((unsigned)(v.w - lo) < (unsigned)RANGE) atomicAdd(&h[v.w - lo], 1);
}

// grid = CNT_C * CNT_R * 2 = 128 blocks. block (c, r, kind).
__global__ __launch_bounds__(512) void k_count(const int* __restrict__ ei,
        int* __restrict__ cnt16, int* __restrict__ deg16, int* __restrict__ pos_e) {
    __shared__ int h[RANGE];
    int bid  = blockIdx.x;
    int c    = bid & 15;
    int r    = (bid >> 4) & 3;
    int kind = bid >> 6;
    int tid  = threadIdx.x;
    for (int i = tid; i < RANGE; i += 512) h[i] = 0;
    __syncthreads();
    int lo = r * RANGE;
    const int4* src = (const int4*)(ei + (size_t)kind * E + (size_t)c * CHUNK);
    int ebase = c * CHUNK;
    if (kind == 0) {
        for (int i = tid; i < HV4; i += 512) {
            int4 a = src[i];
            int4 b = src[i + HV4];
            cnt4_src(a, lo, h, pos_e, ebase + i * 4);
            cnt4_src(b, lo, h, pos_e, ebase + (i + HV4) * 4);
        }
    } else {
        for (int i = tid; i < HV4; i += 512) {
            int4 a = src[i];
            int4 b = src[i + HV4];
            cnt4_dst(a, lo, h);
            cnt4_dst(b, lo, h);
        }
    }
    __syncthreads();
    int* dst = (kind == 0 ? cnt16 : deg16) + (size_t)c * N + lo;
    for (int i = tid; i < RANGE; i += 512) dst[i] = h[i];
}

// fused: 16-copy reduce (deg, cnt, per-copy bases) + scales + block scan
__global__ void k_scan1(const int* __restrict__ cnt16, int* __restrict__ base16,
                        int* __restrict__ off, int* bsum,
                        const int* __restrict__ deg16, float* wsq, float* sdeg) {
    __shared__ int buf[256];
    int tid = threadIdx.x;
    int i = blockIdx.x * 256 + tid;
    int total = 0;
    if (i < N) {
        int run = 0;
        #pragma unroll
        for (int q = 0; q < CNT_C; ++q) {
            base16[q * N + i] = run;
            run += cnt16[q * N + i];
        }
        total = run;
        int deg = 1;                               // self loop
        #pragma unroll
        for (int q = 0; q < CNT_C; ++q) deg += deg16[q * N + i];
        float d = (float)deg;
        wsq[i]  = 1.0f / d;
        sdeg[i] = sqrtf(d);
    }
    buf[tid] = total;
    __syncthreads();
    for (int s = 1; s < 256; s <<= 1) {
        int add = (tid >= s) ? buf[tid - s] : 0;
        __syncthreads();
        buf[tid] += add;
        __syncthreads();
    }
    if (i < N) off[i] = buf[tid] - total;
    if (tid == 255) bsum[blockIdx.x] = buf[255];
}

// r9-kept fused scan2+scan3 + cntg(binary search over sorted batch) + svec init.
// Every block redundantly scans the 196 block-sums (L2-hit cheap) and applies
// its own prefix to off[]; block 0 also does the one-off small inits.
__global__ void k_scan23(int* __restrict__ off, const int* __restrict__ bsum,
                         const int* __restrict__ batch, int* __restrict__ cntg,
                         float* __restrict__ svec) {
    __shared__ int buf[256];
    __shared__ int sL[65];
    int tid = threadIdx.x;
    int v = (tid < SCAN_B) ? bsum[tid] : 0;
    buf[tid] = v;
    __syncthreads();
    for (int s = 1; s < 256; s <<= 1) {
        int add = (tid >= s) ? buf[tid - s] : 0;
        __syncthreads();
        buf[tid] += add;
        __syncthreads();
    }
    int bid = blockIdx.x;
    int pre = buf[bid] - bsum[bid];               // exclusive prefix for this block
    int i = bid * 256 + tid;
    if (i < N) off[i] += pre;
    if (bid == 0) {
        if (tid == 0) off[N] = E;
        // cntg[g] via binary search: batch is sorted ascending in [0, NG)
        if (tid < NG) {
            int lo = 0, hi = N;
            while (lo < hi) {
                int mid = (lo + hi) >> 1;
                if (batch[mid] < tid) lo = mid + 1; else hi = mid;
            }
            sL[tid] = lo;
            if (tid == 0) sL[NG] = N;
        }
        if (tid >= 64 && tid < 192) svec[tid - 64] = 0.f;
        __syncthreads();
        if (tid < NG) cntg[tid] = sL[tid + 1] - sL[tid];
    }
}

// fused: CSR fill (e<E, slot via per-copy base) + U0 row init (e<N)
__global__ void k_fill(const int* __restrict__ ei, const int* __restrict__ off,
                       const int* __restrict__ base16, const int* __restrict__ pos_e,
                       int* __restrict__ mdst,
                       const int* __restrict__ batch, const int* __restrict__ cntg,
                       const float* __restrict__ sdeg, uint4* Z0) {
    int e = blockIdx.x * 256 + threadIdx.x;
    if (e < E) {
        int s = ei[e];
        int q = e / CHUNK;                         // matches k_count's chunking
        mdst[off[s] + base16[q * N + s] + pos_e[e]] = ei[E + e];
    }
    if (e < N) {
        int i = e;
        int g = batch[i];
        int c = cntg[g]; if (c < 1) c = 1;
        float v = (SCALE / (float)c) / sdeg[i];    // dinv = 1/sqrt(deg)
        unsigned int byte = (unsigned int)(__builtin_amdgcn_cvt_pk_fp8_f32(v, v, 0, false) & 0xFF);
        uint4 rows[4];
        #pragma unroll
        for (int q = 0; q < 4; ++q) rows[q] = make_uint4(0u, 0u, 0u, 0u);
        unsigned int* wp = (unsigned int*)rows;
        wp[g >> 2] = byte << (8 * (g & 3));
        #pragma unroll
        for (int q = 0; q < 4; ++q) Z0[(size_t)i * 4 + q] = rows[q];
    }
}

// ---------- hot kernel (r8-frozen): 8 c-lanes/node + int4 idx + 12-deep bursts ----------
__device__ __forceinline__ void add8(floatx2* a, uint2 g) {
    a[0] += __builtin_amdgcn_cvt_pk_f32_fp8(g.x, false);
    a[1] += __builtin_amdgcn_cvt_pk_f32_fp8(g.x, true);
    a[2] += __builtin_amdgcn_cvt_pk_f32_fp8(g.y, false);
    a[3] += __builtin_amdgcn_cvt_pk_f32_fp8(g.y, true);
}

__global__ __launch_bounds__(256, 8) void k_prop(
        const uint2* __restrict__ zin, unsigned long long* __restrict__ zout,
        const int* __restrict__ off, const int* __restrict__ mdst,
        const float* __restrict__ wsq) {
    int t = blockIdx.x * 256 + threadIdx.x;      // N*8 threads
    int node = t >> 3;
    int c    = t & 7;
    if (node >= N) return;                       // no barrier: safe

    floatx2 acc[4];
    #pragma unroll
    for (int k = 0; k < 4; ++k) acc[k] = (floatx2){0.f, 0.f};

    int e  = off[node];
    int e1 = off[node + 1];
    add8(acc, zin[(size_t)node * 8 + c]);        // self term (unweighted in U-form)

    for (; e + 11 < e1; e += 12) {               // 12 gathers in flight
        int4 ia = *(const int4*)(mdst + e);      // 3 vector idx loads
        int4 ib = *(const int4*)(mdst + e + 4);
        int4 ic = *(const int4*)(mdst + e + 8);
        uint2 g0 = zin[(size_t)ia.x * 8 + c];
        uint2 g1 = zin[(size_t)ia.y * 8 + c];
        uint2 g2 = zin[(size_t)ia.z * 8 + c];
        uint2 g3 = zin[(size_t)ia.w * 8 + c];
        uint2 g4 = zin[(size_t)ib.x * 8 + c];
        uint2 g5 = zin[(size_t)ib.y * 8 + c];
        uint2 g6 = zin[(size_t)ib.z * 8 + c];
        uint2 g7 = zin[(size_t)ib.w * 8 + c];
        uint2 g8 = zin[(size_t)ic.x * 8 + c];
        uint2 g9 = zin[(size_t)ic.y * 8 + c];
        uint2 ga = zin[(size_t)ic.z * 8 + c];
        uint2 gb = zin[(size_t)ic.w * 8 + c];
        add8(acc, g0); add8(acc, g1); add8(acc, g2); add8(acc, g3);
        add8(acc, g4); add8(acc, g5); add8(acc, g6); add8(acc, g7);
        add8(acc, g8); add8(acc, g9); add8(acc, ga); add8(acc, gb);
    }
    for (; e + 3 < e1; e += 4) {
        int4 ia = *(const int4*)(mdst + e);
        uint2 g0 = zin[(size_t)ia.x * 8 + c];
        uint2 g1 = zin[(size_t)ia.y * 8 + c];
        uint2 g2 = zin[(size_t)ia.z * 8 + c];
        uint2 g3 = zin[(size_t)ia.w * 8 + c];
        add8(acc, g0); add8(acc, g1); add8(acc, g2); add8(acc, g3);
    }
    for (; e < e1; ++e) {
        add8(acc, zin[(size_t)mdst[e] * 8 + c]);
    }

    float ws = wsq[node];
    unsigned int w0 = pk4(ws * acc[0].x, ws * acc[0].y, ws * acc[1].x, ws * acc[1].y);
    unsigned int w1 = pk4(ws * acc[2].x, ws * acc[2].y, ws * acc[3].x, ws * acc[3].y);
    unsigned long long o = (unsigned long long)w0 | ((unsigned long long)w1 << 32);
    __builtin_nontemporal_store(o, &zout[(size_t)node * 8 + c]);
}

// ---------- colsum: two-stage, two dispatches (r10: reverted -- device-scope
// __threadfence() per block drained dirty L2 784x, 115us vs 8us split) ----------
__global__ void k_colsum1(const unsigned int* __restrict__ Z,
                          const float* __restrict__ sdeg, float* __restrict__ part2) {
    __shared__ float red[256];
    int g = threadIdx.x & 63, sub = threadIdx.x >> 6;
    int w = g >> 2;
    int word = (g >> 1) & 1;
    int odd  = g & 1;
    float acc = 0.f;
    for (int i = blockIdx.x * 4 + sub; i < N; i += gridDim.x * 4) {
        unsigned int u = Z[(size_t)i * 16 + w];
        floatx2 p = word ? __builtin_amdgcn_cvt_pk_f32_fp8(u, true)
                         : __builtin_amdgcn_cvt_pk_f32_fp8(u, false);
        acc += (odd ? p.y : p.x) * sdeg[i];
    }
    red[threadIdx.x] = acc;
    __syncthreads();
    if (sub == 0)
        part2[g * CS1B + blockIdx.x] = red[g] + red[64 + g] + red[128 + g] + red[192 + g];
}

__global__ void k_colsum2(const float* __restrict__ part2, float* __restrict__ sdst) {
    __shared__ float red[256];
    int g = blockIdx.x, tid = threadIdx.x;
    float acc = 0.f;
    for (int b = tid; b < CS1B; b += 256) acc += part2[g * CS1B + b];
    red[tid] = acc;
    __syncthreads();
    for (int s = 128; s >= 1; s >>= 1) {
        if (tid < s) red[tid] += red[tid + s];
        __syncthreads();
    }
    if (tid == 0) sdst[g] = red[0] * INVSCALE;
}

// partial G = (sdeg .* U15)^T X
__global__ __launch_bounds__(256) void k_gpart(
        const uint4* __restrict__ Z, const float4* __restrict__ X,
        const float* __restrict__ sdeg, float* part) {
    __shared__ unsigned int zr[32][16];
    __shared__ float xr[32][128];
    __shared__ float sd[32];
    int tid = threadIdx.x;
    int f4 = tid & 31;
    int gs = tid >> 5;
    float4 acc[8];
    #pragma unroll
    for (int k = 0; k < 8; ++k) acc[k] = make_float4(0.f, 0.f, 0.f, 0.f);

    int per = (N + gridDim.x - 1) / gridDim.x;
    int n0 = blockIdx.x * per;
    int n1 = n0 + per; if (n1 > N) n1 = N;

    for (int nb = n0; nb < n1; nb += 32) {
        __syncthreads();
        if (tid < 128) {
            int nn = tid >> 2, q = tid & 3;
            int node = nb + nn;
            uint4 zv = make_uint4(0u, 0u, 0u, 0u);
            if (node < n1) zv = Z[(size_t)node * 4 + q];
            ((uint4*)&zr[nn][0])[q] = zv;
        }
        if (tid >= 192 && tid < 224) {
            int node = nb + (tid - 192);
            sd[tid - 192] = (node < n1) ? sdeg[node] : 0.f;
        }
        #pragma unroll
        for (int r = 0; r < 4; ++r) {
            int l = r * 256 + tid;
            int nn = l >> 5, c4 = l & 31;
            int node = nb + nn;
            float4 xv = make_float4(0.f, 0.f, 0.f, 0.f);
            if (node < n1) xv = X[(size_t)node * 32 + c4];
            ((float4*)&xr[nn][0])[c4] = xv;
        }
        __syncthreads();
        for (int nn = 0; nn < 32; ++nn) {
            float sc = sd[nn];
            float4 xv = ((const float4*)&xr[nn][0])[f4];
            xv.x *= sc; xv.y *= sc; xv.z *= sc; xv.w *= sc;
            unsigned int za = zr[nn][gs * 2], zb = zr[nn][gs * 2 + 1];
            float zf[8];
            unp4(za, zf); unp4(zb, zf + 4);
            #pragma unroll
            for (int k = 0; k < 8; ++k) {
                acc[k].x += zf[k] * xv.x; acc[k].y += zf[k] * xv.y;
                acc[k].z += zf[k] * xv.z; acc[k].w += zf[k] * xv.w;
            }
        }
    }
    float4* dst = (float4*)(part + (size_t)blockIdx.x * 8192);
    #pragma unroll
    for (int k = 0; k < 8; ++k) dst[(gs * 8 + k) * 32 + f4] = acc[k];
}

__global__ void k_greduce(const float4* __restrict__ part, float4* G) {
    __shared__ float4 red[256];
    int tid = threadIdx.x;
    int o4 = blockIdx.x * 16 + (tid & 15);
    int slice = tid >> 4;
    float4 a = make_float4(0.f, 0.f, 0.f, 0.f);
    #pragma unroll 4
    for (int k = 0; k < GP_BLOCKS / 16; ++k) {
        float4 v = part[(size_t)(slice * (GP_BLOCKS / 16) + k) * 2048 + o4];
        a.x += v.x; a.y += v.y; a.z += v.z; a.w += v.w;
    }
    red[tid] = a;
    __syncthreads();
    for (int s = 128; s >= 16; s >>= 1) {
        if (tid < s) {
            float4 b = red[tid + s];
            red[tid].x += b.x; red[tid].y += b.y; red[tid].z += b.z; red[tid].w += b.w;
        }
        __syncthreads();
    }
    if (tid < 16) {
        float4 r = red[tid];
        G[o4] = make_float4(r.x * INVSCALE, r.y * INVSCALE, r.z * INVSCALE, r.w * INVSCALE);
    }
}

// pass1: [W1;b1] (129x160) @ W2 (160x160) -> T1c
__global__ void k_pass1(const float* __restrict__ W1, const float* __restrict__ b1,
                        const float* __restrict__ W2, float* T1c) {
    int t = blockIdx.x * 256 + threadIdx.x;
    if (t >= 129 * 160) return;
    int m = t / 160, c = t - m * 160;
    const float* arow = (m < 128) ? (W1 + m * 160) : b1;
    float a = 0.f;
    for (int k = 0; k < 160; ++k) a += arow[k] * W2[k * 160 + c];
    T1c[t] = a;
}

// pass2: [T1c; b2] (130x160) @ W3 (160x128) -> TWc
__global__ void k_pass2(const float* __restrict__ T1c, const float* __restrict__ b2,
                        const float* __restrict__ W3, float* TWc) {
    int t = blockIdx.x * 256 + threadIdx.x;
    if (t >= 130 * 128) return;
    int m = t >> 7, c = t & 127;
    const float* arow = (m < 129) ? (T1c + m * 160) : b2;
    float a = 0.f;
    for (int k = 0; k < 160; ++k) a += arow[k] * W3[k * 128 + c];
    TWc[t] = a;
}

__global__ void k_pooled(const float* __restrict__ G, const float* __restrict__ TWc,
                         const float* __restrict__ b3, const float* __restrict__ svec,
                         float* pooled) {
    int t = blockIdx.x * 256 + threadIdx.x;
    if (t >= NG * OUTC) return;
    int g = t >> 7, f = t & 127;
    float a = b3[f] + svec[64 + g] * TWc[128 * 128 + f] + svec[g] * TWc[129 * 128 + f];
    for (int k = 0; k < 128; ++k) a += G[g * 128 + k] * TWc[k * 128 + f];
    pooled[t] = a;
}

__global__ void k_head(const float* __restrict__ pooled, const float* __restrict__ fcw,
                       const float* __restrict__ fcb, float* out) {
    __shared__ float lg[ODIM];
    int g = blockIdx.x, tid = threadIdx.x;
    if (tid < ODIM) {
        float a = fcb[tid];
        for (int k = 0; k < 128; ++k) a += pooled[g * 128 + k] * fcw[k * ODIM + tid];
        lg[tid] = a;
    }
    __syncthreads();
    if (tid == 0) {
        float mx = lg[0];
        for (int j = 1; j < ODIM; ++j) mx = fmaxf(mx, lg[j]);
        float sum = 0.f;
        for (int j = 0; j < ODIM; ++j) sum += expf(lg[j] - mx);
        float lse = mx + logf(sum);
        for (int j = 0; j < ODIM; ++j) out[g * ODIM + j] = lg[j] - lse;
    }
}

extern "C" void kernel_launch(void* const* d_in, const int* in_sizes, int n_in,
                              void* d_out, int out_size, void* d_ws, size_t ws_size,
                              hipStream_t stream) {
    const float* x    = (const float*)d_in[0];
    const int*   ei   = (const int*)d_in[1];
    const int*   batch= (const int*)d_in[2];
    const float* W1   = (const float*)d_in[3];
    const float* b1   = (const float*)d_in[4];
    const float* W2   = (const float*)d_in[5];
    const float* b2   = (const float*)d_in[6];
    const float* W3   = (const float*)d_in[7];
    const float* b3   = (const float*)d_in[8];
    const float* fcw  = (const float*)d_in[9];
    const float* fcb  = (const float*)d_in[10];
    float* out = (float*)d_out;

    char* p = (char*)d_ws;
    auto alloc = [&](size_t bytes) -> void* {
        void* r = (void*)p;
        p += (bytes + 255) & ~(size_t)255;
        return r;
    };
    int*   cnt16   = (int*)  alloc((size_t)CNT_C * N * 4);  // fully written by k_count
    int*   deg16   = (int*)  alloc((size_t)CNT_C * N * 4);  // fully written by k_count
    int*   base16  = (int*)  alloc((size_t)CNT_C * N * 4);
    float* wsq     = (float*)alloc((size_t)N * 4);
    float* sdeg    = (float*)alloc((size_t)N * 4);
    int*   off     = (int*)  alloc((size_t)(N + 1) * 4);
    int*   bsum    = (int*)  alloc((size_t)SCAN_B * 4);
    int*   pos_e   = (int*)  alloc((size_t)E * 4);
    int*   mdst    = (int*)  alloc((size_t)E * 4);
    int*   cntg    = (int*)  alloc((size_t)NG * 4);
    float* svec    = (float*)alloc(128 * 4);
    unsigned char* Z0 = (unsigned char*)alloc((size_t)N * 64);
    unsigned char* Z1 = (unsigned char*)alloc((size_t)N * 64);
    float* part    = (float*)alloc((size_t)GP_BLOCKS * 8192 * 4);
    float* G       = (float*)alloc(8192 * 4);
    float* T1c     = (float*)alloc(129 * 160 * 4);
    float* TWc     = (float*)alloc(130 * 128 * 4);
    float* pooled  = (float*)alloc(64 * 128 * 4);

    int nb_e = (E + 255) / 256;
    k_count<<<CNT_C * CNT_R * 2, 512, 0, stream>>>(ei, cnt16, deg16, pos_e);
    k_scan1<<<SCAN_B, 256, 0, stream>>>(cnt16, base16, off, bsum, deg16, wsq, sdeg);
    k_scan23<<<SCAN_B, 256, 0, stream>>>(off, bsum, batch, cntg, svec);
    k_fill<<<nb_e, 256, 0, stream>>>(ei, off, base16, pos_e, mdst, batch, cntg, sdeg, (uint4*)Z0);

    unsigned char* zc = Z0;
    unsigned char* zn = Z1;
    for (int hop = 1; hop <= 15; ++hop) {
        k_prop<<<PROP_BLOCKS, 256, 0, stream>>>(
            (const uint2*)zc, (unsigned long long*)zn, off, mdst, wsq);
        unsigned char* t = zc; zc = zn; zn = t;
        if (hop == 5) {
            k_colsum1<<<CS1B, 256, 0, stream>>>((const unsigned int*)zc, sdeg, part);
            k_colsum2<<<64, 256, 0, stream>>>(part, svec);
        }
        if (hop == 10) {
            k_colsum1<<<CS1B, 256, 0, stream>>>((const unsigned int*)zc, sdeg, part);
            k_colsum2<<<64, 256, 0, stream>>>(part, svec + 64);
        }
    }

    k_gpart<<<GP_BLOCKS, 256, 0, stream>>>((const uint4*)zc, (const float4*)x, sdeg, part);
    k_greduce<<<128, 256, 0, stream>>>((const float4*)part, (float4*)G);

    k_pass1<<<(129 * 160 + 255) / 256, 256, 0, stream>>>(W1, b1, W2, T1c);
    k_pass2<<<(130 * 128 + 255) / 256, 256, 0, stream>>>(T1c, b2, W3, TWc);
    k_pooled<<<32, 256, 0, stream>>>(G, TWc, b3, svec, pooled);
    k_head<<<NG, 64, 0, stream>>>(pooled, fcw, fcb, out);
}